// Round 14
// baseline (257.838 us; speedup 1.0000x reference)
//
#include <hip/hip_runtime.h>

typedef unsigned int u32;
typedef unsigned long long u64;
typedef float vf4 __attribute__((ext_vector_type(4)));

// ---------------- problem constants ----------------
#define NCLS 80
#define NIMG 8
#define PRE_K 1000
#define POST_K 100
#define PBUF_N 2048

__device__ __forceinline__ int HWof(int l){ return l==0?15200:(l==1?3800:950); }
__device__ __forceinline__ float STRof(int l){ return l==0?8.f:(l==1?16.f:32.f); }
__device__ __forceinline__ u32 CAPof(int l){ return l==0?65536u:32768u; }
__device__ __forceinline__ u32 POFFof(int l){ return l==0?0u:(l==1?65536u:98304u); }

struct Ptrs {
  const float* logits[3];
  const float* reg[3];
  const float* ctr[3];
  const float* cofs[3];
  const float* locs[3];
};

// grid split: 149 lvl0-tiles, 38 lvl1, 10 lvl2 (2048 float4 per tile)
#define NB0 149
#define NB1 38
#define NBALL 197

// ---------------- workspace layout (bytes) ----------------
// zeroed every launch (3328 B):
#define OFF_PCNT  0u            // 24*4 (pad 128)
#define OFF_CAND  128u          // 24*4 (pad 128)
#define OFF_KEEP  256u          // 8*48*8 = 3072
#define ZERO_BYTES 3328u
// not zeroed:
#define OFF_THR   3328u         // 24*8*4 = 768 (written before read)
#define OFF_POOL  4096u         // 8*131072*8 = 8388608
#define OFF_SORT  8392704u      // 24*1024*8 = 196608
#define OFF_MERG  8589312u      // 8*3072*8*4 = 786432   (total ~9.38 MB)

__device__ __forceinline__ float sigmoidf(float x){ return 1.0f/(1.0f+expf(-x)); }

// ---------------- K1: single full-data pass (candidate count + pool) --------
template<int LVL>
__device__ __forceinline__ void collect_body(int tile, int img, const Ptrs& p,
                                             u32* cand, u32* pcnt, u64* pool,
                                             u64* pbuf, u32* shctl){
  constexpr int HW   = LVL==0?15200:(LVL==1?3800:950);
  constexpr int NE   = 80*HW;
  constexpr int NF4  = NE/4;
  const u32 CAP = CAPof(LVL);
  const int pair = img*3 + LVL;
  const size_t poff = (size_t)img*131072u + POFFof(LVL);
  const u32 tbin = (LVL==0?501u:(LVL==1?500u:496u));
  // floors: score >= {0.3125,0.25,0.125}; logit floors {-0.788457,-1.098612,-1.945910}
  const float marg = (LVL==0? -0.7895f : (LVL==1? -1.0996f : -1.9470f));
  const vf4* plane = (const vf4*)(p.logits[LVL] + (size_t)img*NE);
  const float* cptr = p.ctr[LVL] + (size_t)img*HW;
  if (threadIdx.x==0){ shctl[0]=0; shctl[1]=0; }
  __syncthreads();
  // ---- prefetch: 16 independent loads ----
  vf4 vv[8], cc[8];
  #pragma unroll
  for (int k=0;k<8;++k){
    int f4 = tile*2048 + k*256 + (int)threadIdx.x;
    int cf = f4 < NF4 ? f4 : NF4-1;
    vv[k] = plane[cf];
    int e0 = cf*4;
    if (LVL==2){
      vf4 c;
      #pragma unroll
      for (int j=0;j<4;++j){ int e=e0+j; int cl=e/HW; c[j]=cptr[e-cl*HW]; }
      cc[k]=c;
    } else {
      int loc0 = e0 - (e0/HW)*HW;
      cc[k] = *(const vf4*)(cptr + loc0);
    }
  }
  asm volatile("" : "+v"(vv[0]),"+v"(vv[1]),"+v"(vv[2]),"+v"(vv[3]),
                    "+v"(vv[4]),"+v"(vv[5]),"+v"(vv[6]),"+v"(vv[7]),
                    "+v"(cc[0]),"+v"(cc[1]),"+v"(cc[2]),"+v"(cc[3]),
                    "+v"(cc[4]),"+v"(cc[5]),"+v"(cc[6]),"+v"(cc[7]));
  // ---- process from registers ----
  u32 mc = 0;
  #pragma unroll
  for (int k=0;k<8;++k){
    int f4 = tile*2048 + k*256 + (int)threadIdx.x;
    if (f4 < NF4){
      int e0 = f4*4;
      int cls0 = e0 / HW;
      int loc0 = e0 - cls0*HW;
      #pragma unroll
      for (int j=0;j<4;++j){
        float x = vv[k][j];
        if (x > -2.94443898f) mc++;          // sigmoid(x) > 0.05 (monotone)
        if (x > marg){
          float sl = sigmoidf(x);
          float sc = sigmoidf(cc[k][j]);
          u32 bits = __float_as_uint(sl * sc);
          if ((bits>>21) >= tbin){
            int e = e0 + j, cls, loc;
            if (LVL==2){ cls=e/HW; loc=e-cls*HW; } else { cls=cls0; loc=loc0+j; }
            u64 key = ((u64)bits<<32) | (u64)(0xFFFFFFFFu - (u32)(loc*NCLS + cls));
            u32 id = atomicAdd(&shctl[0], 1u);
            if (id < (u32)PBUF_N) pbuf[id] = key;
            else { u32 g = atomicAdd(&pcnt[pair],1u); if (g<CAP) pool[poff+g]=key; }
          }
        }
      }
    }
  }
  if (mc) atomicAdd(&shctl[1], mc);
  __syncthreads();
  u32 m = shctl[0]; if (m > (u32)PBUF_N) m = PBUF_N;
  if (threadIdx.x==0){
    if (m) shctl[2] = atomicAdd(&pcnt[pair], m);
    if (shctl[1]) atomicAdd(&cand[pair], shctl[1]);
  }
  __syncthreads();
  for (u32 i=threadIdx.x; i<m; i+=256){
    u32 d = shctl[2] + i;
    if (d < CAP) pool[poff+d] = pbuf[i];
  }
}

__global__ __launch_bounds__(256)
void fused_pass(Ptrs p, u32* cand, u32* pcnt, u64* pool){
  __shared__ u64 pbuf[PBUF_N];
  __shared__ u32 shctl[4];
  const int bx=(int)blockIdx.x, img=(int)blockIdx.y;
  if (bx<NB0)          collect_body<0>(bx,        img,p,cand,pcnt,pool,pbuf,shctl);
  else if (bx<NB0+NB1) collect_body<1>(bx-NB0,    img,p,cand,pcnt,pool,pbuf,shctl);
  else                 collect_body<2>(bx-NB0-NB1,img,p,cand,pcnt,pool,pbuf,shctl);
}

// ---------------- slow-path helpers (only when pool insufficient) -----------
template<int LVL>
__device__ __forceinline__ void slow_hist(const Ptrs& p, int img, u32* h){
  constexpr int HW = LVL==0?15200:(LVL==1?3800:950);
  constexpr int NE = 80*HW, NF4 = NE/4;
  const vf4* plane = (const vf4*)(p.logits[LVL] + (size_t)img*NE);
  const float* cptr = p.ctr[LVL] + (size_t)img*HW;
  for (int f4=(int)threadIdx.x; f4<NF4; f4+=1024){
    vf4 v = plane[f4];
    int e0=f4*4;
    #pragma unroll
    for (int j=0;j<4;++j){
      float sl=sigmoidf(v[j]);
      if (sl>0.05f){
        int e=e0+j; int c=e/HW; int loc=e-c*HW;
        u32 bits=__float_as_uint(sl*sigmoidf(cptr[loc]));
        atomicAdd(&h[bits>>21],1u);
      }
    }
  }
}
template<int LVL>
__device__ __forceinline__ void slow_refill(const Ptrs& p, int img, u32 B1,
                                            u64* pool, size_t poff, u32* cnt){
  constexpr int HW = LVL==0?15200:(LVL==1?3800:950);
  constexpr int NE = 80*HW, NF4 = NE/4;
  const u32 CAP = CAPof(LVL);
  const vf4* plane = (const vf4*)(p.logits[LVL] + (size_t)img*NE);
  const float* cptr = p.ctr[LVL] + (size_t)img*HW;
  for (int f4=(int)threadIdx.x; f4<NF4; f4+=1024){
    vf4 v = plane[f4];
    int e0=f4*4;
    #pragma unroll
    for (int j=0;j<4;++j){
      float sl=sigmoidf(v[j]);
      if (sl>0.05f){
        int e=e0+j; int c=e/HW; int loc=e-c*HW;
        u32 bits=__float_as_uint(sl*sigmoidf(cptr[loc]));
        if ((bits>>21) >= B1){
          u32 id = atomicAdd(cnt,1u);
          if (id<CAP) pool[poff+id] = ((u64)bits<<32) |
                        (u64)(0xFFFFFFFFu - (u32)(loc*NCLS + c));
        }
      }
    }
  }
}

// ---------------- K2: fused select + sort (24 independent per-pair blocks) ---
__global__ __launch_bounds__(1024)
void selsort(Ptrs p, const u32* cand, const u32* pcnt, u32* thr,
             u64* pool, u64* sorted){
  const int pair=(int)blockIdx.x, lvl=pair%3, img=pair/3;
  const int tid=(int)threadIdx.x;
  __shared__ u64 a[2048];
  __shared__ u32 h[512];
  __shared__ u32 h2[2048];
  __shared__ u32 seg[256], exc[256];
  __shared__ u32 sB1, sCnt, sT22, sgc, scnt;
  const size_t poff = (size_t)img*131072u + POFFof(lvl);
  const u32 CAP = CAPof(lvl);
  const u32 kk = min(cand[pair], (u32)PRE_K);
  if (kk==0){ if (tid==0) thr[pair*8+3]=0u; return; }
  const u32 pcRaw = pcnt[pair];
  const bool ok = (pcRaw <= CAP) && (pcRaw >= kk);
  u32 pc = min(pcRaw, CAP);

  // ---- coarse 512-bin hist ----
  for (int b=tid;b<512;b+=1024) h[b]=0;
  __syncthreads();
  if (ok){
    for (u32 i=tid;i<pc;i+=1024) atomicAdd(&h[(u32)(pool[poff+i]>>53)],1u);
  } else {
    if (lvl==0)      slow_hist<0>(p,img,h);
    else if (lvl==1) slow_hist<1>(p,img,h);
    else             slow_hist<2>(p,img,h);
  }
  __syncthreads();
  if (tid<256) seg[tid] = h[511-2*tid] + h[511-(2*tid+1)];
  __syncthreads();
  if (tid==0){ u32 run=0; for(int i=0;i<256;++i){ exc[i]=run; run+=seg[i]; } }
  __syncthreads();
  if (tid<256){
    u32 cum=exc[tid];
    #pragma unroll
    for (int q=0;q<2;++q){
      int bin=511-(2*tid+q); u32 c=h[bin];
      if (c && cum<kk && cum+c>=kk){ sB1=(u32)bin; sCnt=cum; }
      cum+=c;
    }
  }
  __syncthreads();
  const u32 B1=sB1, cntAb=sCnt;
  if (!ok){
    if (tid==0) sgc=0;
    __syncthreads();
    if (lvl==0)      slow_refill<0>(p,img,B1,pool,poff,&sgc);
    else if (lvl==1) slow_refill<1>(p,img,B1,pool,poff,&sgc);
    else             slow_refill<2>(p,img,B1,pool,poff,&sgc);
    __syncthreads();
    pc = min(sgc, CAP);
  }
  // ---- fine 2048-bin hist within bin B1 ----
  for (int b=tid;b<2048;b+=1024) h2[b]=0;
  __syncthreads();
  for (u32 i=tid;i<pc;i+=1024){
    u64 key=pool[poff+i];
    if ((u32)(key>>53)==B1) atomicAdd(&h2[(u32)(key>>42)&0x7FFu],1u);
  }
  __syncthreads();
  const u32 KK2 = kk - cntAb;
  if (tid<256){
    u32 part=0;
    #pragma unroll
    for (int q=0;q<8;++q) part += h2[2047-(tid*8+q)];
    seg[tid]=part;
  }
  __syncthreads();
  if (tid==0){ u32 run=0; for(int i=0;i<256;++i){ exc[i]=run; run+=seg[i]; } }
  __syncthreads();
  if (tid<256){
    u32 cum=exc[tid];
    #pragma unroll
    for (int q=0;q<8;++q){
      int bin=2047-(tid*8+q); u32 c=h2[bin];
      if (c && cum<KK2 && cum+c>=KK2) sT22=(B1<<11)|(u32)bin;
      cum+=c;
    }
  }
  __syncthreads();
  const u32 T22=sT22;
  // ---- gather keys >= T22, bitonic 2048 descending, emit top-kk ----
  for (int i=tid;i<2048;i+=1024) a[i]=0ull;
  if (tid==0) scnt=0;
  __syncthreads();
  for (u32 i=tid;i<pc;i+=1024){
    u64 k = pool[poff+i];
    if ((u32)(k>>42) >= T22){
      u32 id = atomicAdd(&scnt,1u);
      if (id < 2048u) a[id]=k;
    }
  }
  __syncthreads();
  const u32 n = min(scnt, 2048u);
  for (int k=2;k<=2048;k<<=1){
    for (int j=k>>1;j>0;j>>=1){
      for (int t=tid;t<2048;t+=1024){
        int ix = t ^ j;
        if (ix > t){
          u64 x=a[t], y=a[ix];
          bool up = ((t & k)==0);
          if (up ? (x<y) : (x>y)){ a[t]=y; a[ix]=x; }
        }
      }
      __syncthreads();
    }
  }
  u32 m = kk < n ? kk : n;
  for (u32 r=tid;r<m;r+=1024) sorted[(size_t)pair*1024+r]=a[r];
  if (tid==0) thr[pair*8+3]=m;
}

// ---------------- K3: per-class NMS with analytic merge positions ------------
// Global merged order = (bits desc, level asc, rank asc). For a member at
// (l, r): pos = r + sum_{o<l} countGE(bits, level o) + sum_{o>l} countGT(bits)
// — identical to merge_kernel's binary-search rank (concat tie-break is
// always-true for o<l, always-false for o>l). Kept boxes write their merged
// record (box decode = merge's exact fp-contract-off expression) + gkeep bit.
__global__ __launch_bounds__(64)
void nms_class(Ptrs p, const u32* thr, const u64* sorted_all,
               u64* gkeep, float* merged_all){
#pragma clang fp contract(off)
  const int c = (int)blockIdx.x, img = (int)blockIdx.y;
  const int lane = (int)threadIdx.x;
  __shared__ u64 lv[3][1024];      // 24 KB
  __shared__ u32 mem[4096];        // 16 KB  (pos<<12 | l<<10 | r)
  __shared__ float4 kbox[1024];    // 16 KB
  __shared__ int sn[3];
  if (lane < 3) sn[lane] = (int)thr[(img*3+lane)*8+3];
  __syncthreads();
  for (int i=lane; i<3*1024; i+=64){
    int l = i>>10, r = i&1023;
    lv[l][r] = (r < sn[l]) ? sorted_all[(size_t)(img*3+l)*1024 + r] : 0ull;
  }
  __syncthreads();
  // ---- collect members of class c with global positions ----
  const u64 lanemask = (lane==0)?0ull:((~0ull)>>(64-lane));
  u32 base = 0;
  for (int l=0;l<3;++l){
    const int nl = sn[l];
    for (int t0=0;t0<nl;t0+=64){
      int r = t0+lane;
      bool ismem = false;
      u32 pos = 0;
      if (r < nl){
        u64 key = lv[l][r];
        u32 flat = 0xFFFFFFFFu - (u32)key;
        if ((int)(flat % (u32)NCLS) == c){
          ismem = true;
          u32 bits = (u32)(key>>32);
          pos = (u32)r;
          #pragma unroll
          for (int o=0;o<3;++o) if (o!=l){
            int lo=0, hi=sn[o];
            if (o<l){ while (lo<hi){ int m=(lo+hi)>>1; if ((u32)(lv[o][m]>>32) >= bits) lo=m+1; else hi=m; } }
            else    { while (lo<hi){ int m=(lo+hi)>>1; if ((u32)(lv[o][m]>>32) >  bits) lo=m+1; else hi=m; } }
            pos += (u32)lo;
          }
        }
      }
      u64 word = __ballot(ismem);
      if (ismem){
        u32 rank = base + (u32)__popcll(word & lanemask);
        mem[rank] = (pos<<12) | ((u32)l<<10) | (u32)r;
      }
      base += (u32)__popcll(word);
    }
  }
  const int n = (int)base;
  if (n == 0) return;
  __syncthreads();
  // ---- sort members by pos ascending (pos in high bits) ----
  int np2 = 64; while (np2 < n) np2 <<= 1;
  for (int i=lane+n; i<np2; i+=64) mem[i] = 0xFFFFFFFFu;
  __syncthreads();
  for (int k=2;k<=np2;k<<=1){
    for (int j=k>>1;j>0;j>>=1){
      for (int t=lane;t<np2;t+=64){
        int ix = t^j;
        if (ix>t){
          u32 x=mem[t], y=mem[ix];
          bool up = ((t&k)==0);
          if (up ? (x>y) : (x<y)){ mem[t]=y; mem[ix]=x; }
        }
      }
      __syncthreads();
    }
  }
  // ---- greedy in tiles of 64 ----
  const float off = (float)c * 1217.0f;
  float* merged = merged_all + (size_t)img*3072*8;
  int kc = 0;
  for (int t0=0;t0<n;t0+=64){
    int r = t0+lane;
    bool valid = (r<n);
    float4 bx = make_float4(0.f,0.f,0.f,0.f);
    float u0=0.f,u1=0.f,u2=0.f,u3=0.f, score=0.f;
    int loc=0, ml=0, ppos=0;
    if (valid){
      u32 m = mem[r];
      ppos = (int)(m>>12); ml=(int)((m>>10)&3u); int rr=(int)(m&1023u);
      u64 key = lv[ml][rr];
      u32 flat = 0xFFFFFFFFu - (u32)key;
      score = __uint_as_float((u32)(key>>32));
      loc = (int)(flat/(u32)NCLS);
      int HW = HWof(ml);
      float lx = p.locs[ml][2*loc], ly = p.locs[ml][2*loc+1];
      float st = STRof(ml);
      const float* rg = p.reg[ml] + (size_t)img*4*HW + loc;
      float r0 = rg[0]*st, r1v = rg[HW]*st, r2 = rg[2*(size_t)HW]*st, r3 = rg[3*(size_t)HW]*st;
      u0 = fminf(fmaxf(lx - r0, 0.f), 1216.f);
      u1 = fminf(fmaxf(ly - r1v, 0.f),  800.f);
      u2 = fminf(fmaxf(lx + r2, 0.f), 1216.f);
      u3 = fminf(fmaxf(ly + r3, 0.f),  800.f);
      bx = make_float4(u0+off, u1+off, u2+off, u3+off);
    }
    float ax = (bx.z-bx.x)*(bx.w-bx.y);
    bool alive_l = valid;
    for (int q=0; q<kc; ++q){
      float4 bq = kbox[q];
      float aq = (bq.z-bq.x)*(bq.w-bq.y);
      float ltx=fmaxf(bq.x,bx.x), lty=fmaxf(bq.y,bx.y);
      float rbx=fminf(bq.z,bx.z), rby=fminf(bq.w,bx.w);
      float wx=fmaxf(rbx-ltx,0.f), wy=fmaxf(rby-lty,0.f);
      float inter=wx*wy;
      float denom=aq+ax; denom=denom-inter; denom=denom+1e-9f;
      if (alive_l && (inter/denom > 0.6f)) alive_l=false;
    }
    u64 alive = __ballot(alive_l);
    while (alive){
      int i = __ffsll((unsigned long long)alive) - 1;
      float kx0=__shfl(u0,i), ky0=__shfl(u1,i), kx1=__shfl(u2,i), ky1=__shfl(u3,i);
      float ks=__shfl(score,i);
      int   kloc=__shfl(loc,i), kl=__shfl(ml,i), kpos=__shfl(ppos,i);
      float bix=kx0+off, biy=ky0+off, biz=kx1+off, biw=ky1+off;
      if (lane==0){
        atomicOr((unsigned long long*)&gkeep[img*48 + (kpos>>6)], 1ull<<(kpos&63));
        float* o = merged + (size_t)kpos*8;
        o[0]=kx0; o[1]=ky0; o[2]=kx1; o[3]=ky1;
        o[4]=ks; o[5]=(float)c; o[6]=(float)kl; o[7]=(float)kloc;
        if (kc < 1024) kbox[kc] = make_float4(bix,biy,biz,biw);
      }
      kc++;
      float ai=(biz-bix)*(biw-biy);
      float ltx=fmaxf(bix,bx.x), lty=fmaxf(biy,bx.y);
      float rbx=fminf(biz,bx.z), rby=fminf(biw,bx.w);
      float wx=fmaxf(rbx-ltx,0.f), wy=fmaxf(rby-lty,0.f);
      float inter=wx*wy;
      float denom=ai+ax; denom=denom-inter; denom=denom+1e-9f;
      bool supp = alive_l && (inter/denom > 0.6f);   // keeper lane: IoU=1 -> self-cleared
      u64 killm = __ballot(supp);
      alive &= ~killm;
      alive &= ~(1ull<<i);
      alive_l = alive_l && !supp;
    }
    __syncthreads();   // kbox visible before next tile
  }
}

// ---------------- K4: fused emit — one block per (row,img) ----------------
__global__ __launch_bounds__(128)
void emit_kernel(Ptrs p, const float* merged_all, const u64* gkeep, float* out){
  const int r = (int)blockIdx.x, img = (int)blockIdx.y;
  const int tid = (int)threadIdx.x;
  __shared__ int s_i, s_kept;
  if (tid < 64){
    u64 word = (tid < 48) ? gkeep[img*48 + tid] : 0ull;
    int c = (int)__popcll(word);
    int inc = c;
    #pragma unroll
    for (int d=1; d<64; d<<=1){
      int y = __shfl_up(inc, d);
      if (tid >= d) inc += y;
    }
    int excl = inc - c;
    int total = __shfl(inc, 63);
    int kept = total < POST_K ? total : POST_K;
    if (tid==0){ s_kept = kept; s_i = -1; }
    bool sel = (tid<48) && (r < kept) && (excl <= r) && (r < excl + c);
    if (sel){
      u64 w = word; int need = r - excl;
      for (int q=0;q<need;++q) w &= w-1ull;
      s_i = (tid<<6) + (int)__ffsll((unsigned long long)w) - 1;
    }
  }
  __syncthreads();
  const int i = s_i; const int kept = s_kept;
  const bool has = (r < kept) && (i >= 0);
  const float* rec = merged_all + (size_t)img*3072*8 + (size_t)(has?i:0)*8;
  float* obx = out;
  float* osc = out + 3200;
  float* ocl = out + 4000;
  float* ocf = out + 4800;
  float* okv = out + 107200;
  if (tid==0) osc[img*POST_K+r] = has ? sqrtf(fmaxf(rec[4], 1e-12f)) : 0.f;
  if (tid==1) ocl[img*POST_K+r] = has ? rec[5] : -1.0f;
  if (tid==2) okv[img*POST_K+r] = has ? 1.0f : 0.f;
  if (tid>=4 && tid<8) obx[(img*POST_K+r)*4 + (tid-4)] = has ? rec[tid-4] : 0.f;
  float v = 0.f;
  if (has){
    int l = (int)rec[6]; int loc = (int)rec[7];
    int HW = HWof(l);
    v = p.cofs[l][((size_t)img*128 + tid)*HW + loc];
  }
  ocf[(img*POST_K + r)*128 + tid] = v;
}

// ---------------- host ----------------
extern "C" void kernel_launch(void* const* d_in, const int* in_sizes, int n_in,
                              void* d_out, int out_size, void* d_ws, size_t ws_size,
                              hipStream_t stream){
  Ptrs p;
  for (int l=0; l<3; ++l){
    p.locs[l]   = (const float*)d_in[5*l+0];
    p.logits[l] = (const float*)d_in[5*l+1];
    p.reg[l]    = (const float*)d_in[5*l+2];
    p.ctr[l]    = (const float*)d_in[5*l+3];
    p.cofs[l]   = (const float*)d_in[5*l+4];
  }
  char* ws = (char*)d_ws;
  u32* pcnt   = (u32*)(ws + OFF_PCNT);
  u32* cand   = (u32*)(ws + OFF_CAND);
  u64* gkeep  = (u64*)(ws + OFF_KEEP);
  u32* thr    = (u32*)(ws + OFF_THR);
  u64* pool   = (u64*)(ws + OFF_POOL);
  u64* sorted = (u64*)(ws + OFF_SORT);
  float* merged = (float*)(ws + OFF_MERG);

  hipMemsetAsync(ws, 0, ZERO_BYTES, stream);
  fused_pass<<<dim3(NBALL,8), 256, 0, stream>>>(p, cand, pcnt, pool);
  selsort<<<24, 1024, 0, stream>>>(p, cand, pcnt, thr, pool, sorted);
  nms_class<<<dim3(NCLS,8), 64, 0, stream>>>(p, thr, sorted, gkeep, merged);
  emit_kernel<<<dim3(POST_K,8), 128, 0, stream>>>(p, merged, gkeep, (float*)d_out);
}

// Round 15
// 162.845 us; speedup vs baseline: 1.5833x; 1.5833x over previous
//
#include <hip/hip_runtime.h>

typedef unsigned int u32;
typedef unsigned long long u64;

// ---------------- problem constants ----------------
#define NCLS 80
#define NIMG 8
#define PRE_K 1000
#define POST_K 100
#define PBUF_N 2048

__device__ __forceinline__ int HWof(int l){ return l==0?15200:(l==1?3800:950); }
__device__ __forceinline__ float STRof(int l){ return l==0?8.f:(l==1?16.f:32.f); }
__device__ __forceinline__ u32 CAPof(int l){ return l==0?65536u:32768u; }
__device__ __forceinline__ u32 POFFof(int l){ return l==0?0u:(l==1?65536u:98304u); }

struct Ptrs {
  const float* logits[3];
  const float* reg[3];
  const float* ctr[3];
  const float* cofs[3];
  const float* locs[3];
};

// grid split: 149 lvl0-tiles, 38 lvl1, 10 lvl2 (2048 float4 per tile)
#define NB0 149
#define NB1 38
#define NBALL 197

// ---------------- workspace layout (bytes) ----------------
// zeroed every launch (3392 B only):
#define OFF_PCNT  0u            // 24*4 (pad 128)
#define OFF_CAND  128u          // 24*4 (pad 128)
#define OFF_MCNT  256u          // 32 (pad 64)
#define OFF_KEEP  320u          // 8*48*8 = 3072
#define ZERO_BYTES 3392u
// not zeroed:
#define OFF_THR   3392u         // 24*8*4 = 768 (written before read)
#define OFF_POOL  4224u         // 8*131072*8 = 8388608
#define OFF_SORT  8392832u      // 24*1024*8 = 196608
#define OFF_CLS   8589440u      // 8*3072*4 = 98304
#define OFF_MERG  8687744u      // 8*3072*8*4 = 786432   (total ~9.47 MB)

__device__ __forceinline__ float sigmoidf(float x){ return 1.0f/(1.0f+expf(-x)); }

// ---------------- K1: single full-data pass (candidate count + pool) --------
// Scores: sigmoid(logit) * sigmoid(ctr), inline (validated bit-identical).
// No histogram: per-thread candidate counter (1 LDS atomic/thread) + pool push
// for coarse bin >= static floor {501,500,496} (score >= {0.3125,0.25,0.125}).
template<int LVL>
__device__ __forceinline__ void collect_body(int tile, int img, const Ptrs& p,
                                             u32* cand, u32* pcnt, u64* pool,
                                             u64* pbuf, u32* shctl){
  constexpr int HW   = LVL==0?15200:(LVL==1?3800:950);
  constexpr int NE   = 80*HW;
  constexpr int NF4  = NE/4;
  const u32 CAP = CAPof(LVL);
  const int pair = img*3 + LVL;
  const size_t poff = (size_t)img*131072u + POFFof(LVL);
  const u32 tbin = (LVL==0?501u:(LVL==1?500u:496u));
  const float4* plane = (const float4*)(p.logits[LVL] + (size_t)img*NE);
  const float* cptr = p.ctr[LVL] + (size_t)img*HW;
  if (threadIdx.x==0){ shctl[0]=0; shctl[1]=0; }
  __syncthreads();
  u32 mc = 0;
  #pragma unroll
  for (int k=0;k<8;++k){
    int f4 = tile*2048 + k*256 + (int)threadIdx.x;
    if (f4 < NF4){
      float4 v = plane[f4];
      int e0 = f4*4;
      int cls0 = e0 / HW;
      int loc0 = e0 - cls0*HW;
      float ss[4];
      if (LVL==2){                        // HW=950 not %4: rows can split a float4
        #pragma unroll
        for (int j=0;j<4;++j){ int e=e0+j; int c=e/HW; ss[j]=sigmoidf(cptr[e-c*HW]); }
      } else {                            // HW%4==0: aligned float4 ctr load
        float4 c4 = *(const float4*)(cptr + loc0);
        ss[0]=sigmoidf(c4.x); ss[1]=sigmoidf(c4.y); ss[2]=sigmoidf(c4.z); ss[3]=sigmoidf(c4.w);
      }
      float vv[4] = {v.x,v.y,v.z,v.w};
      #pragma unroll
      for (int j=0;j<4;++j){
        float sl = sigmoidf(vv[j]);
        if (sl > 0.05f){
          mc++;
          u32 bits = __float_as_uint(sl * ss[j]);
          if ((bits>>21) >= tbin){
            int e = e0 + j, cls, loc;
            if (LVL==2){ cls=e/HW; loc=e-cls*HW; } else { cls=cls0; loc=loc0+j; }
            u64 key = ((u64)bits<<32) | (u64)(0xFFFFFFFFu - (u32)(loc*NCLS + cls));
            u32 id = atomicAdd(&shctl[0], 1u);
            if (id < (u32)PBUF_N) pbuf[id] = key;
            else { u32 g = atomicAdd(&pcnt[pair],1u); if (g<CAP) pool[poff+g]=key; }
          }
        }
      }
    }
  }
  if (mc) atomicAdd(&shctl[1], mc);
  __syncthreads();
  u32 m = shctl[0]; if (m > (u32)PBUF_N) m = PBUF_N;
  if (threadIdx.x==0){
    if (m) shctl[2] = atomicAdd(&pcnt[pair], m);
    if (shctl[1]) atomicAdd(&cand[pair], shctl[1]);
  }
  __syncthreads();
  for (u32 i=threadIdx.x; i<m; i+=256){
    u32 d = shctl[2] + i;
    if (d < CAP) pool[poff+d] = pbuf[i];
  }
}

__global__ __launch_bounds__(256)
void fused_pass(Ptrs p, u32* cand, u32* pcnt, u64* pool){
  __shared__ u64 pbuf[PBUF_N];
  __shared__ u32 shctl[4];
  const int bx=(int)blockIdx.x, img=(int)blockIdx.y;
  if (bx<NB0)          collect_body<0>(bx,        img,p,cand,pcnt,pool,pbuf,shctl);
  else if (bx<NB0+NB1) collect_body<1>(bx-NB0,    img,p,cand,pcnt,pool,pbuf,shctl);
  else                 collect_body<2>(bx-NB0-NB1,img,p,cand,pcnt,pool,pbuf,shctl);
}

// ---------------- slow-path helpers (only when pool insufficient) -----------
template<int LVL>
__device__ __forceinline__ void slow_hist(const Ptrs& p, int img, u32* h){
  constexpr int HW = LVL==0?15200:(LVL==1?3800:950);
  constexpr int NE = 80*HW, NF4 = NE/4;
  const float4* plane = (const float4*)(p.logits[LVL] + (size_t)img*NE);
  const float* cptr = p.ctr[LVL] + (size_t)img*HW;
  for (int f4=(int)threadIdx.x; f4<NF4; f4+=1024){
    float4 v = plane[f4];
    int e0=f4*4;
    float vv[4]={v.x,v.y,v.z,v.w};
    #pragma unroll
    for (int j=0;j<4;++j){
      float sl=sigmoidf(vv[j]);
      if (sl>0.05f){
        int e=e0+j; int c=e/HW; int loc=e-c*HW;
        u32 bits=__float_as_uint(sl*sigmoidf(cptr[loc]));
        atomicAdd(&h[bits>>21],1u);
      }
    }
  }
}
template<int LVL>
__device__ __forceinline__ void slow_refill(const Ptrs& p, int img, u32 B1,
                                            u64* pool, size_t poff, u32* cnt){
  constexpr int HW = LVL==0?15200:(LVL==1?3800:950);
  constexpr int NE = 80*HW, NF4 = NE/4;
  const u32 CAP = CAPof(LVL);
  const float4* plane = (const float4*)(p.logits[LVL] + (size_t)img*NE);
  const float* cptr = p.ctr[LVL] + (size_t)img*HW;
  for (int f4=(int)threadIdx.x; f4<NF4; f4+=1024){
    float4 v = plane[f4];
    int e0=f4*4;
    float vv[4]={v.x,v.y,v.z,v.w};
    #pragma unroll
    for (int j=0;j<4;++j){
      float sl=sigmoidf(vv[j]);
      if (sl>0.05f){
        int e=e0+j; int c=e/HW; int loc=e-c*HW;
        u32 bits=__float_as_uint(sl*sigmoidf(cptr[loc]));
        if ((bits>>21) >= B1){
          u32 id = atomicAdd(cnt,1u);
          if (id<CAP) pool[poff+id] = ((u64)bits<<32) |
                        (u64)(0xFFFFFFFFu - (u32)(loc*NCLS + c));
        }
      }
    }
  }
}

// ---------------- K2: fused select + sort (24 independent per-pair blocks) ---
__global__ __launch_bounds__(1024)
void selsort(Ptrs p, const u32* cand, const u32* pcnt, u32* thr,
             u64* pool, u64* sorted){
  const int pair=(int)blockIdx.x, lvl=pair%3, img=pair/3;
  const int tid=(int)threadIdx.x;
  __shared__ u64 a[2048];
  __shared__ u32 h[512];
  __shared__ u32 h2[2048];
  __shared__ u32 seg[256], exc[256];
  __shared__ u32 sB1, sCnt, sT22, sgc, scnt;
  const size_t poff = (size_t)img*131072u + POFFof(lvl);
  const u32 CAP = CAPof(lvl);
  const u32 kk = min(cand[pair], (u32)PRE_K);
  if (kk==0){ if (tid==0) thr[pair*8+3]=0u; return; }
  const u32 pcRaw = pcnt[pair];
  const bool ok = (pcRaw <= CAP) && (pcRaw >= kk);
  u32 pc = min(pcRaw, CAP);

  // ---- coarse 512-bin hist ----
  for (int b=tid;b<512;b+=1024) h[b]=0;
  __syncthreads();
  if (ok){
    for (u32 i=tid;i<pc;i+=1024) atomicAdd(&h[(u32)(pool[poff+i]>>53)],1u);
  } else {
    if (lvl==0)      slow_hist<0>(p,img,h);
    else if (lvl==1) slow_hist<1>(p,img,h);
    else             slow_hist<2>(p,img,h);
  }
  __syncthreads();
  if (tid<256) seg[tid] = h[511-2*tid] + h[511-(2*tid+1)];
  __syncthreads();
  if (tid==0){ u32 run=0; for(int i=0;i<256;++i){ exc[i]=run; run+=seg[i]; } }
  __syncthreads();
  if (tid<256){
    u32 cum=exc[tid];
    #pragma unroll
    for (int q=0;q<2;++q){
      int bin=511-(2*tid+q); u32 c=h[bin];
      if (c && cum<kk && cum+c>=kk){ sB1=(u32)bin; sCnt=cum; }
      cum+=c;
    }
  }
  __syncthreads();
  const u32 B1=sB1, cntAb=sCnt;
  if (!ok){
    if (tid==0) sgc=0;
    __syncthreads();
    if (lvl==0)      slow_refill<0>(p,img,B1,pool,poff,&sgc);
    else if (lvl==1) slow_refill<1>(p,img,B1,pool,poff,&sgc);
    else             slow_refill<2>(p,img,B1,pool,poff,&sgc);
    __syncthreads();
    pc = min(sgc, CAP);
  }
  // ---- fine 2048-bin hist within bin B1 ----
  for (int b=tid;b<2048;b+=1024) h2[b]=0;
  __syncthreads();
  for (u32 i=tid;i<pc;i+=1024){
    u64 key=pool[poff+i];
    if ((u32)(key>>53)==B1) atomicAdd(&h2[(u32)(key>>42)&0x7FFu],1u);
  }
  __syncthreads();
  const u32 KK2 = kk - cntAb;
  if (tid<256){
    u32 part=0;
    #pragma unroll
    for (int q=0;q<8;++q) part += h2[2047-(tid*8+q)];
    seg[tid]=part;
  }
  __syncthreads();
  if (tid==0){ u32 run=0; for(int i=0;i<256;++i){ exc[i]=run; run+=seg[i]; } }
  __syncthreads();
  if (tid<256){
    u32 cum=exc[tid];
    #pragma unroll
    for (int q=0;q<8;++q){
      int bin=2047-(tid*8+q); u32 c=h2[bin];
      if (c && cum<KK2 && cum+c>=KK2) sT22=(B1<<11)|(u32)bin;
      cum+=c;
    }
  }
  __syncthreads();
  const u32 T22=sT22;
  // ---- gather keys >= T22, bitonic 2048 descending, emit top-kk ----
  for (int i=tid;i<2048;i+=1024) a[i]=0ull;
  if (tid==0) scnt=0;
  __syncthreads();
  for (u32 i=tid;i<pc;i+=1024){
    u64 k = pool[poff+i];
    if ((u32)(k>>42) >= T22){
      u32 id = atomicAdd(&scnt,1u);
      if (id < 2048u) a[id]=k;
    }
  }
  __syncthreads();
  const u32 n = min(scnt, 2048u);
  for (int k=2;k<=2048;k<<=1){
    for (int j=k>>1;j>0;j>>=1){
      for (int t=tid;t<2048;t+=1024){
        int ix = t ^ j;
        if (ix > t){
          u64 x=a[t], y=a[ix];
          bool up = ((t & k)==0);
          if (up ? (x<y) : (x>y)){ a[t]=y; a[ix]=x; }
        }
      }
      __syncthreads();
    }
  }
  u32 m = kk < n ? kk : n;
  for (u32 r=tid;r<m;r+=1024) sorted[(size_t)pair*1024+r]=a[r];
  if (tid==0) thr[pair*8+3]=m;
}

// ---------------- K3: 3-way stable merge + box decode (+ class array) --------
__global__ void merge_kernel(Ptrs p, const u32* thr, const u64* sorted,
                             float* merged, float* clsarr, u32* mcnt){
#pragma clang fp contract(off)
  const int img = blockIdx.x;
  __shared__ u64 mk[3][1024];
  __shared__ int n[3];
  if (threadIdx.x < 3) n[threadIdx.x] = (int)thr[(img*3+threadIdx.x)*8+3];
  __syncthreads();
  const int n0=n[0], n1=n[1], n2=n[2];
  for (int idx=threadIdx.x; idx<3*1024; idx+=blockDim.x){
    int l = idx>>10, r = idx&1023;
    if (r < n[l]){
      u64 key = sorted[(size_t)(img*3+l)*1024 + r];
      mk[l][r] = (key & 0xFFFFFFFF00000000ull) |
                 (u64)(0xFFFFFFFFu - (u32)(l*PRE_K + r));  // concat-idx tie-break
    }
  }
  __syncthreads();
  const int T = n0+n1+n2;
  if (threadIdx.x==0) mcnt[img] = (u32)T;
  for (int t=threadIdx.x; t<T; t+=blockDim.x){
    int l, r;
    if (t < n0){ l=0; r=t; }
    else if (t < n0+n1){ l=1; r=t-n0; }
    else { l=2; r=t-n0-n1; }
    u64 x = mk[l][r];
    int pos = r;
    #pragma unroll
    for (int o=0;o<3;++o) if (o!=l){
      int lo=0, hi=n[o];
      while (lo<hi){ int m=(lo+hi)>>1; if (mk[o][m] > x) lo=m+1; else hi=m; }
      pos += lo;
    }
    u64 key = sorted[(size_t)(img*3+l)*1024 + r];
    u32 flat = 0xFFFFFFFFu - (u32)(key & 0xFFFFFFFFull);
    float score = __uint_as_float((u32)(key>>32));
    int HW = HWof(l);
    int loc = (int)(flat / (u32)NCLS);
    int cls = (int)(flat - (u32)loc*NCLS);
    float lx = p.locs[l][2*loc], ly = p.locs[l][2*loc+1];
    float st = STRof(l);
    const float* rg = p.reg[l] + (size_t)img*4*HW + loc;
    float r0 = rg[0]*st, r1 = rg[HW]*st, r2 = rg[2*(size_t)HW]*st, r3 = rg[3*(size_t)HW]*st;
    float x1 = fminf(fmaxf(lx - r0, 0.f), 1216.f);
    float y1 = fminf(fmaxf(ly - r1, 0.f),  800.f);
    float x2 = fminf(fmaxf(lx + r2, 0.f), 1216.f);
    float y2 = fminf(fmaxf(ly + r3, 0.f),  800.f);
    float* out = merged + (size_t)(img*3072 + pos)*8;
    out[0]=x1; out[1]=y1; out[2]=x2; out[3]=y2;
    out[4]=score; out[5]=(float)cls; out[6]=(float)l; out[7]=(float)loc;
    clsarr[img*3072 + pos] = (float)cls;
  }
}

// ---------------- K4: per-class greedy NMS (640 independent tasks) ----------
__global__ __launch_bounds__(64)
void nms_class(const float* merged_all, const float* clsarr, const u32* mcnt, u64* gkeep){
#pragma clang fp contract(off)
  const int c = (int)blockIdx.x, img = (int)blockIdx.y;
  const float* merged = merged_all + (size_t)img*3072*8;
  const float* carr = clsarr + (size_t)img*3072;
  const int T = (int)mcnt[img];
  const int lane = (int)threadIdx.x;
  __shared__ unsigned short mlist[3072];
  __shared__ float4 kbox[1024];

  float fv[48];
  #pragma unroll
  for (int w=0; w<48; ++w){
    int j = w*64 + lane;
    fv[w] = (j < T) ? carr[j] : -1.0f;
  }
  int base = 0;
  const u64 lanemask = (lane==0) ? 0ull : ((~0ull) >> (64-lane));
  #pragma unroll
  for (int w=0; w<48; ++w){
    bool mem = ((int)fv[w] == c);
    u64 word = __ballot(mem);
    if (mem){
      int rank = base + (int)__popcll(word & lanemask);
      mlist[rank] = (unsigned short)(w*64 + lane);
    }
    base += (int)__popcll(word);
  }
  const int n = base;
  if (n == 0) return;
  __syncthreads();

  const float off = (float)c * 1217.0f;
  int kc = 0;
  for (int t0 = 0; t0 < n; t0 += 64){
    int r = t0 + lane;
    bool valid = (r < n);
    float4 bx = make_float4(0.f,0.f,0.f,0.f);
    int gj = 0;
    if (valid){
      gj = (int)mlist[r];
      const float* rec = merged + (size_t)gj*8;
      bx = make_float4(rec[0]+off, rec[1]+off, rec[2]+off, rec[3]+off);
    }
    float ax = (bx.z-bx.x)*(bx.w-bx.y);
    bool alive_l = valid;
    for (int q=0; q<kc; ++q){
      float4 bq = kbox[q];
      float aq = (bq.z-bq.x)*(bq.w-bq.y);
      float ltx=fmaxf(bq.x,bx.x), lty=fmaxf(bq.y,bx.y);
      float rbx=fminf(bq.z,bx.z), rby=fminf(bq.w,bx.w);
      float wx=fmaxf(rbx-ltx,0.f), wy=fmaxf(rby-lty,0.f);
      float inter=wx*wy;
      float denom=aq+ax; denom=denom-inter; denom=denom+1e-9f;
      if (alive_l && (inter/denom > 0.6f)) alive_l=false;
    }
    u64 alive = __ballot(alive_l);
    while (alive){
      int i = __ffsll((unsigned long long)alive) - 1;
      float bix=__shfl(bx.x,i), biy=__shfl(bx.y,i), biz=__shfl(bx.z,i), biw=__shfl(bx.w,i);
      int gi = __shfl(gj, i);
      if (lane==0){
        atomicOr((unsigned long long*)&gkeep[img*48 + (gi>>6)], 1ull<<(gi&63));
        if (kc < 1024) kbox[kc] = make_float4(bix,biy,biz,biw);
      }
      kc++;
      float ai=(biz-bix)*(biw-biy);
      float ltx=fmaxf(bix,bx.x), lty=fmaxf(biy,bx.y);
      float rbx=fminf(biz,bx.z), rby=fminf(biw,bx.w);
      float wx=fmaxf(rbx-ltx,0.f), wy=fmaxf(rby-lty,0.f);
      float inter=wx*wy;
      float denom=ai+ax; denom=denom-inter; denom=denom+1e-9f;
      bool supp = alive_l && (inter/denom > 0.6f);
      u64 killm = __ballot(supp);
      alive &= ~killm;
      alive &= ~(1ull<<i);
      alive_l = alive_l && !supp;
    }
    __syncthreads();
  }
}

// ---------------- K5: fused emit — one block per (row,img) ----------------
__global__ __launch_bounds__(128)
void emit_kernel(Ptrs p, const float* merged_all, const u64* gkeep, float* out){
  const int r = (int)blockIdx.x, img = (int)blockIdx.y;
  const int tid = (int)threadIdx.x;
  __shared__ int s_i, s_kept;
  if (tid < 64){
    u64 word = (tid < 48) ? gkeep[img*48 + tid] : 0ull;
    int c = (int)__popcll(word);
    int inc = c;
    #pragma unroll
    for (int d=1; d<64; d<<=1){
      int y = __shfl_up(inc, d);
      if (tid >= d) inc += y;
    }
    int excl = inc - c;
    int total = __shfl(inc, 63);
    int kept = total < POST_K ? total : POST_K;
    if (tid==0){ s_kept = kept; s_i = -1; }
    bool sel = (tid<48) && (r < kept) && (excl <= r) && (r < excl + c);
    if (sel){
      u64 w = word; int need = r - excl;
      for (int q=0;q<need;++q) w &= w-1ull;
      s_i = (tid<<6) + (int)__ffsll((unsigned long long)w) - 1;
    }
  }
  __syncthreads();
  const int i = s_i; const int kept = s_kept;
  const bool has = (r < kept) && (i >= 0);
  const float* rec = merged_all + (size_t)img*3072*8 + (size_t)(has?i:0)*8;
  float* obx = out;
  float* osc = out + 3200;
  float* ocl = out + 4000;
  float* ocf = out + 4800;
  float* okv = out + 107200;
  if (tid==0) osc[img*POST_K+r] = has ? sqrtf(fmaxf(rec[4], 1e-12f)) : 0.f;
  if (tid==1) ocl[img*POST_K+r] = has ? rec[5] : -1.0f;
  if (tid==2) okv[img*POST_K+r] = has ? 1.0f : 0.f;
  if (tid>=4 && tid<8) obx[(img*POST_K+r)*4 + (tid-4)] = has ? rec[tid-4] : 0.f;
  float v = 0.f;
  if (has){
    int l = (int)rec[6]; int loc = (int)rec[7];
    int HW = HWof(l);
    v = p.cofs[l][((size_t)img*128 + tid)*HW + loc];
  }
  ocf[(img*POST_K + r)*128 + tid] = v;
}

// ---------------- host ----------------
extern "C" void kernel_launch(void* const* d_in, const int* in_sizes, int n_in,
                              void* d_out, int out_size, void* d_ws, size_t ws_size,
                              hipStream_t stream){
  Ptrs p;
  for (int l=0; l<3; ++l){
    p.locs[l]   = (const float*)d_in[5*l+0];
    p.logits[l] = (const float*)d_in[5*l+1];
    p.reg[l]    = (const float*)d_in[5*l+2];
    p.ctr[l]    = (const float*)d_in[5*l+3];
    p.cofs[l]   = (const float*)d_in[5*l+4];
  }
  char* ws = (char*)d_ws;
  u32* pcnt   = (u32*)(ws + OFF_PCNT);
  u32* cand   = (u32*)(ws + OFF_CAND);
  u32* mcnt   = (u32*)(ws + OFF_MCNT);
  u64* gkeep  = (u64*)(ws + OFF_KEEP);
  u32* thr    = (u32*)(ws + OFF_THR);
  u64* pool   = (u64*)(ws + OFF_POOL);
  u64* sorted = (u64*)(ws + OFF_SORT);
  float* clsarr = (float*)(ws + OFF_CLS);
  float* merged = (float*)(ws + OFF_MERG);

  hipMemsetAsync(ws, 0, ZERO_BYTES, stream);
  fused_pass<<<dim3(NBALL,8), 256, 0, stream>>>(p, cand, pcnt, pool);
  selsort<<<24, 1024, 0, stream>>>(p, cand, pcnt, thr, pool, sorted);
  merge_kernel<<<8, 1024, 0, stream>>>(p, thr, sorted, merged, clsarr, mcnt);
  nms_class<<<dim3(NCLS,8), 64, 0, stream>>>(merged, clsarr, mcnt, gkeep);
  emit_kernel<<<dim3(POST_K,8), 128, 0, stream>>>(p, merged, gkeep, (float*)d_out);
}